// Round 8
// baseline (743.368 us; speedup 1.0000x reference)
//
#include <hip/hip_runtime.h>
#include <hip/hip_bf16.h>

#define NBR   8
#define DV    256    // VOCAB
#define FF    1024   // FFN
#define RT    256    // rows per block tile
#define NCHUNK 16    // FFN chunks of 64
#define NROWS 16384

// LDS (bytes): B1 dbuf 2x32K @0 | B2 dbuf 2x32K @64K | Hs [256][64] 32K @128K = 160K
#define L_B1   0
#define L_B2   65536
#define L_HS   131072
#define LDS_BYTES 163840

using bf16x8 = __attribute__((ext_vector_type(8))) short;
using f32x4  = __attribute__((ext_vector_type(4))) float;

__device__ __forceinline__ unsigned short f2bf(float f) {
    unsigned int u = __builtin_bit_cast(unsigned int, f);
    unsigned int r = (u + 0x7fffu + ((u >> 16) & 1u)) >> 16;
    return (unsigned short)r;
}
// gelu(x) ~= x * sigmoid(1.595769122x + 0.0713548163x^3), exp2 domain
__device__ __forceinline__ float gelu_fast(float x) {
    float x2 = x * x;
    float z  = x * fmaf(x2, -0.1029434959f, -2.3022078770f);
    float e  = __builtin_amdgcn_exp2f(z);
    return x * __builtin_amdgcn_rcpf(1.0f + e);
}

#define GLL(gsrc, ldst) __builtin_amdgcn_global_load_lds((const unsigned int*)(gsrc), (unsigned int*)(ldst), 16, 0, 0)
#define MFMA16 __builtin_amdgcn_mfma_f32_16x16x32_bf16
#define BAR()     do { asm volatile("" ::: "memory"); __builtin_amdgcn_s_barrier(); asm volatile("" ::: "memory"); } while (0)
#define LGKM0()   asm volatile("s_waitcnt lgkmcnt(0)" ::: "memory")
#define VMCNT(N)  asm volatile("s_waitcnt vmcnt(" #N ")" ::: "memory")

// ---------------- prep: fp32 weights -> bf16 swizzled LDS chunk images ----------------
// w1img per (n,c): 32KB Bt1 [64 nn][256 kk]: val = U1[n][kk][c*64+nn], byte ^= (nn&7)<<4
// w2img per (n,c): 32KB Bt2 [256 nn][64 kk]: val = U2[n][c*64+kk][nn], byte ^= (nn&7)<<4
__global__ void prep_weights(const float* __restrict__ U1, const float* __restrict__ U2,
                             unsigned short* __restrict__ w1img, unsigned short* __restrict__ w2img)
{
    const int b = blockIdx.x;          // 0..127 : n*16 + c
    const int n = b >> 4, cch = b & 15;
    const int tid = threadIdx.x;       // 0..255
    char* img1 = (char*)(w1img) + ((size_t)b << 15);
    char* img2 = (char*)(w2img) + ((size_t)b << 15);
    const float* U1n = U1 + (size_t)n * DV * FF;
    const float* U2n = U2 + (size_t)n * FF * DV;
    #pragma unroll 4
    for (int e = 0; e < 64; ++e) {
        int kk = e * 4 + (tid >> 6);
        int nn = tid & 63;
        float v = U1n[(size_t)kk * FF + cch * 64 + nn];
        unsigned off = ((unsigned)(nn * 256 + kk) * 2u) ^ (unsigned)((nn & 7) << 4);
        *(unsigned short*)(img1 + off) = f2bf(v);
    }
    #pragma unroll 4
    for (int e = 0; e < 64; ++e) {
        int nn = tid;  // 0..255
        float v = U2n[(size_t)(cch * 64 + e) * DV + nn];
        unsigned off = ((unsigned)(nn * 64 + e) * 2u) ^ (unsigned)((nn & 7) << 4);
        *(unsigned short*)(img2 + off) = f2bf(v);
    }
}

// ---------------- main: 16 waves (4 waves/SIMD), 2-phase, counted vmcnt ----------------
__global__ __launch_bounds__(1024, 4)
void belayer_main(const float* __restrict__ x,
                  const unsigned short* __restrict__ w1img,
                  const unsigned short* __restrict__ w2img,
                  const float* __restrict__ b1g, const float* __restrict__ b2g,
                  const float* __restrict__ lnw, const float* __restrict__ lnb,
                  float* __restrict__ out)
{
    __shared__ __align__(16) char LDS[LDS_BYTES];
    const int tid  = threadIdx.x;
    const int lane = tid & 63;
    const int wave = tid >> 6;          // 0..15
    const int q = lane >> 4, c = lane & 15;
    const int n    = blockIdx.x & 7;    // branch == XCD affinity
    const int tile = blockIdx.x >> 3;   // 0..63
    const int row0 = tile * RT;
    const int rowg  = wave >> 1, colsel = wave & 1;   // G1: 32 rows x 32 ffn per wave (8x2)
    const int rowg2 = wave >> 2, colg2  = wave & 3;   // G2: 64 rows x 64 cols per wave (4x4)
    const unsigned swz = (unsigned)((c & 7) << 4);

    // staging: each of 16 waves covers 2KB of each 32KB image: 2 GLL x 1KB
    const char* g1base = (const char*)w1img + ((size_t)(n * NCHUNK) << 15) + (wave << 11) + lane * 16;
    const char* g2base = (const char*)w2img + ((size_t)(n * NCHUNK) << 15) + (wave << 11) + lane * 16;

    // ---- A-frags from global x FIRST (loads+converts fully before GLLs) ----
    bf16x8 A[2][8];
    #pragma unroll
    for (int rf = 0; rf < 2; ++rf) {
        const float* src = x + (((size_t)(row0 + rowg * 32 + rf * 16 + c)) * NBR + n) * DV + q * 8;
        #pragma unroll
        for (int ks = 0; ks < 8; ++ks) {
            f32x4 v0 = *(const f32x4*)(src + ks * 32);
            f32x4 v1 = *(const f32x4*)(src + ks * 32 + 4);
            bf16x8 h;
            h[0] = (short)f2bf(v0[0]); h[1] = (short)f2bf(v0[1]);
            h[2] = (short)f2bf(v0[2]); h[3] = (short)f2bf(v0[3]);
            h[4] = (short)f2bf(v1[0]); h[5] = (short)f2bf(v1[1]);
            h[6] = (short)f2bf(v1[2]); h[7] = (short)f2bf(v1[3]);
            A[rf][ks] = h;
        }
    }
    // ---- prologue staging: B1[0] (2 GLL, older) then B2[0] (2 GLL, newer) ----
    {
        char* l1 = LDS + L_B1 + (wave << 11);
        GLL(g1base, l1); GLL(g1base + 1024, l1 + 1024);
        char* l2 = LDS + L_B2 + (wave << 11);
        GLL(g2base, l2); GLL(g2base + 1024, l2 + 1024);
    }

    // ---- swizzled LDS addresses (swz toggles bits 4-6; hi-bit adds are safe) ----
    const unsigned nn1  = (unsigned)(colsel * 32 + c);
    const unsigned aB1e = (nn1 * 512 + q * 16) ^ swz;          // +cf*8192, +(ks>>1)*128
    const unsigned aB1o = (nn1 * 512 + q * 16 + 64) ^ swz;
    const unsigned rr2  = (unsigned)(rowg2 * 64 + c);
    const unsigned aHe  = (rr2 * 128 + q * 16) ^ swz;          // +rf*2048
    const unsigned aHo  = (rr2 * 128 + q * 16 + 64) ^ swz;
    const unsigned nn2  = (unsigned)(colg2 * 64 + c);
    const unsigned aB2e = (nn2 * 128 + q * 16) ^ swz;          // +cf*2048
    const unsigned aB2o = (nn2 * 128 + q * 16 + 64) ^ swz;
    unsigned aW[4][2];
    #pragma unroll
    for (int r = 0; r < 4; ++r)
        #pragma unroll
        for (int cf = 0; cf < 2; ++cf)
            aW[r][cf] = (unsigned)(((rowg * 32 + q * 4 + r) * 128 + (colsel * 32 + cf * 16 + c) * 2)
                                   ^ (((q * 4 + r) & 7) << 4));   // +rf*2048

    f32x4 acc2[4][4];
    #pragma unroll
    for (int i = 0; i < 4; ++i)
        #pragma unroll
        for (int j = 0; j < 4; ++j) acc2[i][j] = (f32x4){0.f, 0.f, 0.f, 0.f};

    VMCNT(2);    // drain B1[0]; keep B2[0] in flight
    BAR();

    for (int t = 0; t < NCHUNK; ++t) {
        const int tsrc = (t < NCHUNK - 1) ? (t + 1) : (NCHUNK - 1);  // clamp: dummy reload keeps vmcnt uniform
        const unsigned hb1 = L_B1 + ((unsigned)(t & 1) << 15);
        const unsigned hb2 = L_B2 + ((unsigned)(t & 1) << 15);

        // ================= PH_A: G1[t] -> Hs ; stage B1[t+1] =================
        // bias loads FIRST (older than the GLLs, so consuming them keeps GLLs airborne)
        float b1v0 = b1g[n * FF + t * 64 + colsel * 32 + c];
        float b1v1 = b1g[n * FF + t * 64 + colsel * 32 + 16 + c];
        {
            const char* g = g1base + ((size_t)tsrc << 15);
            char* l = LDS + L_B1 + (((t + 1) & 1) << 15) + (wave << 11);
            GLL(g, l); GLL(g + 1024, l + 1024);
        }
        #pragma unroll
        for (int cf = 0; cf < 2; ++cf) {
            f32x4 a0 = (f32x4){0.f, 0.f, 0.f, 0.f};
            f32x4 a1 = (f32x4){0.f, 0.f, 0.f, 0.f};
            #pragma unroll
            for (int ks = 0; ks < 8; ++ks) {
                const unsigned addr = ((ks & 1) ? aB1o : aB1e) + hb1 + (unsigned)cf * 8192 + (unsigned)(ks >> 1) * 128;
                bf16x8 b = *(const bf16x8*)(LDS + addr);
                a0 = MFMA16(A[0][ks], b, a0, 0, 0, 0);
                a1 = MFMA16(A[1][ks], b, a1, 0, 0, 0);
            }
            float bv = cf ? b1v1 : b1v0;
            #pragma unroll
            for (int rf = 0; rf < 2; ++rf) {
                f32x4 av = rf ? a1 : a0;
                #pragma unroll
                for (int r = 0; r < 4; ++r) {
                    float g = gelu_fast(av[r] + bv);
                    *(unsigned short*)(LDS + L_HS + aW[r][cf] + (unsigned)rf * 2048) = f2bf(g);
                }
            }
        }
        LGKM0();     // Hs writes drained
        VMCNT(2);    // drain B2[t] (older); keep B1[t+1]
        BAR();       // Hs[t] + B2[t] published

        // ================= PH_B: G2[t] accumulate ; stage B2[t+1] =================
        {
            const char* g = g2base + ((size_t)tsrc << 15);
            char* l = LDS + L_B2 + (((t + 1) & 1) << 15) + (wave << 11);
            GLL(g, l); GLL(g + 1024, l + 1024);
        }
        #pragma unroll
        for (int ks = 0; ks < 2; ++ks) {
            bf16x8 bfr[4];
            #pragma unroll
            for (int cf = 0; cf < 4; ++cf)
                bfr[cf] = *(const bf16x8*)(LDS + hb2 + (ks ? aB2o : aB2e) + (unsigned)cf * 2048);
            #pragma unroll
            for (int rf = 0; rf < 4; ++rf) {
                bf16x8 a = *(const bf16x8*)(LDS + L_HS + (ks ? aHo : aHe) + (unsigned)rf * 2048);
                __builtin_amdgcn_s_setprio(1);
                #pragma unroll
                for (int cf = 0; cf < 4; ++cf)
                    acc2[rf][cf] = MFMA16(a, bfr[cf], acc2[rf][cf], 0, 0, 0);
                __builtin_amdgcn_s_setprio(0);
            }
        }
        VMCNT(2);    // drain B1[t+1] (older); keep B2[t+1]
        BAR();       // B1[t+1] published; Hs reads done -> Hs free for G1[t+1]
    }

    // ---- epilogue: +b2, cross-wave LN(256), gelu, +skip, store ----
    float b2v[4];
    #pragma unroll
    for (int cf = 0; cf < 4; ++cf) b2v[cf] = b2g[n * DV + colg2 * 64 + cf * 16 + c];

    float sA[4][4], sQ[4][4];
    #pragma unroll
    for (int rf = 0; rf < 4; ++rf)
        #pragma unroll
        for (int r = 0; r < 4; ++r) { sA[rf][r] = 0.f; sQ[rf][r] = 0.f; }
    #pragma unroll
    for (int rf = 0; rf < 4; ++rf)
        #pragma unroll
        for (int cf = 0; cf < 4; ++cf)
            #pragma unroll
            for (int r = 0; r < 4; ++r) {
                float v = acc2[rf][cf][r] + b2v[cf];
                acc2[rf][cf][r] = v;
                sA[rf][r] += v;
                sQ[rf][r] += v * v;
            }
    #pragma unroll
    for (int m = 1; m < 16; m <<= 1)
        #pragma unroll
        for (int rf = 0; rf < 4; ++rf)
            #pragma unroll
            for (int r = 0; r < 4; ++r) {
                sA[rf][r] += __shfl_xor(sA[rf][r], m, 64);
                sQ[rf][r] += __shfl_xor(sQ[rf][r], m, 64);
            }
    float* Lred = (float*)(LDS + L_HS);   // 8KB scratch over Hs (all G2 reads done at loop-end BAR)
    if (c == 0) {
        #pragma unroll
        for (int rf = 0; rf < 4; ++rf)
            #pragma unroll
            for (int r = 0; r < 4; ++r) {
                int row = rowg2 * 64 + rf * 16 + q * 4 + r;
                Lred[colg2 * 256 + row]        = sA[rf][r];
                Lred[1024 + colg2 * 256 + row] = sQ[rf][r];
            }
    }
    __syncthreads();
    float mu[4][4], rs[4][4];
    #pragma unroll
    for (int rf = 0; rf < 4; ++rf)
        #pragma unroll
        for (int r = 0; r < 4; ++r) {
            int row = rowg2 * 64 + rf * 16 + q * 4 + r;
            float ssum = Lred[row] + Lred[256 + row] + Lred[512 + row] + Lred[768 + row];
            float qsum = Lred[1024 + row] + Lred[1280 + row] + Lred[1536 + row] + Lred[1792 + row];
            float m_ = ssum * (1.0f / 256.0f);
            float var = qsum * (1.0f / 256.0f) - m_ * m_;
            mu[rf][r] = m_;
            rs[rf][r] = rsqrtf(var + 1e-5f);
        }
    #pragma unroll
    for (int cf = 0; cf < 4; ++cf) {
        int col = colg2 * 64 + cf * 16 + c;
        float lw = lnw[col];
        float lb = lnb[col];
        #pragma unroll
        for (int rf = 0; rf < 4; ++rf)
            #pragma unroll
            for (int r = 0; r < 4; ++r) {
                int row = rowg2 * 64 + rf * 16 + q * 4 + r;
                float v = (acc2[rf][cf][r] - mu[rf][r]) * rs[rf][r] * lw + lb;
                float g = gelu_fast(v);
                size_t oi = ((size_t)(row0 + row) * NBR + n) * DV + col;
                out[oi] = x[oi] + g;
            }
    }
}

extern "C" void kernel_launch(void* const* d_in, const int* in_sizes, int n_in,
                              void* d_out, int out_size, void* d_ws, size_t ws_size,
                              hipStream_t stream) {
    const float* x   = (const float*)d_in[0];
    const float* U1  = (const float*)d_in[1];
    const float* b1  = (const float*)d_in[2];
    const float* U2  = (const float*)d_in[3];
    const float* b2  = (const float*)d_in[4];
    const float* lnw = (const float*)d_in[5];
    const float* lnb = (const float*)d_in[6];
    float* out = (float*)d_out;

    unsigned short* w1img = (unsigned short*)d_ws;               // 4 MB
    unsigned short* w2img = w1img + (size_t)4 * 1024 * 1024 / 2; // 4 MB

    prep_weights<<<dim3(128), dim3(256), 0, stream>>>(U1, U2, w1img, w2img);
    belayer_main<<<dim3((NROWS / RT) * NBR), dim3(1024), 0, stream>>>(x, w1img, w2img, b1, b2, lnw, lnb, out);
}

// Round 9
// 229.706 us; speedup vs baseline: 3.2362x; 3.2362x over previous
//
#include <hip/hip_runtime.h>
#include <hip/hip_bf16.h>

#define NBR   8
#define DV    256    // VOCAB
#define FF    1024   // FFN
#define RT    64     // rows per block
#define NCH   32     // FFN chunks of 32
#define NROWS 16384

// LDS: B1 dbuf 2x16K @0 | B2 dbuf 2x16K @32K | Hs 4K @64K  = 68K -> 2 blocks/CU
#define L_B1 0
#define L_B2 32768
#define L_HS 65536
#define LDS_BYTES 69632

using bf16x8 = __attribute__((ext_vector_type(8))) short;
using f32x4  = __attribute__((ext_vector_type(4))) float;

__device__ __forceinline__ unsigned short f2bf(float f) {
    unsigned int u = __builtin_bit_cast(unsigned int, f);
    unsigned int r = (u + 0x7fffu + ((u >> 16) & 1u)) >> 16;
    return (unsigned short)r;
}
// gelu(x) ~= x * sigmoid(1.595769122x + 0.0713548163x^3), exp2 domain
__device__ __forceinline__ float gelu_fast(float x) {
    float x2 = x * x;
    float z  = x * fmaf(x2, -0.1029434959f, -2.3022078770f);
    float e  = __builtin_amdgcn_exp2f(z);
    return x * __builtin_amdgcn_rcpf(1.0f + e);
}

#define GLL(gsrc, ldst) __builtin_amdgcn_global_load_lds((const unsigned int*)(gsrc), (unsigned int*)(ldst), 16, 0, 0)
#define MFMA16 __builtin_amdgcn_mfma_f32_16x16x32_bf16

// ---------------- prep: fp32 weights -> bf16 kk-group-major chunk images ----------------
// img1 per (n,cch) [16KB]: elem(kkg,nn,j) at byte kkg*512+nn*16+j*2 = U1[n][kkg*8+j][cch*32+nn]
//   (kkg in [0,32) over K=256, nn in [0,32) chunk ffn)
// img2 per (n,cch) [16KB]: elem(q,nn,j) at byte q*4096+nn*16+j*2 = U2[n][cch*32+q*8+j][nn]
//   (q in [0,4) over chunk K=32, nn in [0,256) vocab col)
__global__ void prep_weights(const float* __restrict__ U1, const float* __restrict__ U2,
                             unsigned short* __restrict__ w1img, unsigned short* __restrict__ w2img)
{
    const int b = blockIdx.x;          // 0..255 = n*32 + cch
    const int n = b >> 5, cch = b & 31;
    const int tid = threadIdx.x;       // 0..255
    char* img1 = (char*)w1img + ((size_t)b << 14);
    char* img2 = (char*)w2img + ((size_t)b << 14);
    const float* U1n = U1 + (size_t)n * DV * FF;
    const float* U2n = U2 + (size_t)n * FF * DV;
    #pragma unroll
    for (int e = 0; e < 4; ++e) {
        int p = tid + e * 256;
        int kkg = p >> 5, nn = p & 31;
        bf16x8 h;
        #pragma unroll
        for (int j = 0; j < 8; ++j)
            h[j] = (short)f2bf(U1n[(size_t)(kkg * 8 + j) * FF + cch * 32 + nn]);
        *(bf16x8*)(img1 + kkg * 512 + nn * 16) = h;
    }
    #pragma unroll
    for (int e = 0; e < 4; ++e) {
        int p = tid + e * 256;
        int qq = p >> 8, nn = p & 255;
        bf16x8 h;
        #pragma unroll
        for (int j = 0; j < 8; ++j)
            h[j] = (short)f2bf(U2n[(size_t)(cch * 32 + qq * 8 + j) * DV + nn]);
        *(bf16x8*)(img2 + qq * 4096 + nn * 16) = h;
    }
}

// ---------------- main: 64-row blocks, 8 waves, 2 blocks/CU (4 waves/SIMD) ----------------
__global__ __launch_bounds__(512, 4)
void belayer_main(const float* __restrict__ x,
                  const unsigned short* __restrict__ w1img,
                  const unsigned short* __restrict__ w2img,
                  const float* __restrict__ b1g, const float* __restrict__ b2g,
                  const float* __restrict__ lnw, const float* __restrict__ lnb,
                  float* __restrict__ out)
{
    __shared__ __align__(16) char LDS[LDS_BYTES];
    const int tid  = threadIdx.x;
    const int lane = tid & 63;
    const int wave = tid >> 6;          // 0..7
    const int q = lane >> 4, c = lane & 15;
    const int n    = blockIdx.x & 7;    // branch == XCD affinity
    const int tile = blockIdx.x >> 3;   // 0..255
    const int row0 = tile * RT;
    const int rowg   = wave >> 1;       // 0..3: rows rowg*16 (both GEMMs)
    const int colsel = wave & 1;        // G1: ffn half; G2: vocab col half

    const char* g1base = (const char*)w1img + ((size_t)(n * NCH) << 14) + (wave << 11) + lane * 16;
    const char* g2base = (const char*)w2img + ((size_t)(n * NCH) << 14) + (wave << 11) + lane * 16;
    char* l1base = LDS + L_B1 + (wave << 11);
    char* l2base = LDS + L_B2 + (wave << 11);

#define STAGE1(T) do { const char* g_ = g1base + ((size_t)(T) << 14); \
        char* l_ = l1base + (((T) & 1) << 14); GLL(g_, l_); GLL(g_ + 1024, l_ + 1024); } while (0)
#define STAGE2(T) do { const char* g_ = g2base + ((size_t)(T) << 14); \
        char* l_ = l2base + (((T) & 1) << 14); GLL(g_, l_); GLL(g_ + 1024, l_ + 1024); } while (0)

    STAGE1(0); STAGE2(0);

    // ---- A-frags resident (32 VGPR): row = rowg*16 + c, kk = ks*32 + q*8 ----
    bf16x8 A[8];
    {
        const float* src = x + (((size_t)(row0 + rowg * 16 + c)) * NBR + n) * DV + q * 8;
        #pragma unroll
        for (int ks = 0; ks < 8; ++ks) {
            f32x4 v0 = *(const f32x4*)(src + ks * 32);
            f32x4 v1 = *(const f32x4*)(src + ks * 32 + 4);
            bf16x8 h;
            h[0] = (short)f2bf(v0[0]); h[1] = (short)f2bf(v0[1]);
            h[2] = (short)f2bf(v0[2]); h[3] = (short)f2bf(v0[3]);
            h[4] = (short)f2bf(v1[0]); h[5] = (short)f2bf(v1[1]);
            h[6] = (short)f2bf(v1[2]); h[7] = (short)f2bf(v1[3]);
            A[ks] = h;
        }
    }

    // ---- LDS addresses (kk-group-major images: conflict-free by construction) ----
    const unsigned aB1 = (unsigned)(q * 512 + (colsel * 16 + c) * 16);    // + half + ks*2048
    const unsigned aB2 = (unsigned)(q * 4096 + (colsel * 128 + c) * 16);  // + half + cf*256
    const unsigned aH  = (unsigned)(q * 1024 + (rowg * 16 + c) * 16);
    unsigned aW[4];
    #pragma unroll
    for (int r = 0; r < 4; ++r)
        aW[r] = (unsigned)((colsel * 2 + (c >> 3)) * 1024 + (rowg * 16 + q * 4 + r) * 16 + (c & 7) * 2);

    f32x4 acc2[8];
    #pragma unroll
    for (int i = 0; i < 8; ++i) acc2[i] = (f32x4){0.f, 0.f, 0.f, 0.f};

    __syncthreads();   // B1[0], B2[0] staged & visible

    for (int t = 0; t < NCH; ++t) {
        const unsigned h1 = L_B1 + ((unsigned)(t & 1) << 14);
        const unsigned h2 = L_B2 + ((unsigned)(t & 1) << 14);

        // ===== PH_A: stage B1[t+1]; G1[t]: 8 MFMA; bias+gelu -> Hs =====
        if (t + 1 < NCH) STAGE1(t + 1);
        float b1v = b1g[n * FF + t * 32 + colsel * 16 + c];
        f32x4 acc1 = (f32x4){0.f, 0.f, 0.f, 0.f};
        #pragma unroll
        for (int ks = 0; ks < 8; ++ks) {
            bf16x8 b = *(const bf16x8*)(LDS + h1 + aB1 + ks * 2048);
            acc1 = MFMA16(A[ks], b, acc1, 0, 0, 0);
        }
        #pragma unroll
        for (int r = 0; r < 4; ++r) {
            float g = gelu_fast(acc1[r] + b1v);
            *(unsigned short*)(LDS + L_HS + aW[r]) = f2bf(g);
        }
        __syncthreads();   // Hs[t] + B2[t](staged prev phase) visible; drains GLLs

        // ===== PH_B: stage B2[t+1]; G2[t]: 8 MFMA accumulate =====
        if (t + 1 < NCH) STAGE2(t + 1);
        bf16x8 a = *(const bf16x8*)(LDS + L_HS + aH);
        #pragma unroll
        for (int cf = 0; cf < 8; ++cf) {
            bf16x8 b = *(const bf16x8*)(LDS + h2 + aB2 + cf * 256);
            acc2[cf] = MFMA16(a, b, acc2[cf], 0, 0, 0);
        }
        __syncthreads();   // Hs readers done (free for G1[t+1]); B1[t+1] visible
    }

    // ---- epilogue: +b2, LN(256) (16-lane reduce + colsel-pair via LDS), gelu, +skip ----
    float b2v[8];
    #pragma unroll
    for (int cf = 0; cf < 8; ++cf) b2v[cf] = b2g[n * DV + colsel * 128 + cf * 16 + c];

    float s[4] = {0.f, 0.f, 0.f, 0.f}, sq[4] = {0.f, 0.f, 0.f, 0.f};
    #pragma unroll
    for (int cf = 0; cf < 8; ++cf)
        #pragma unroll
        for (int r = 0; r < 4; ++r) {
            float v = acc2[cf][r] + b2v[cf];
            acc2[cf][r] = v;
            s[r]  += v;
            sq[r] += v * v;
        }
    #pragma unroll
    for (int m = 1; m < 16; m <<= 1)
        #pragma unroll
        for (int r = 0; r < 4; ++r) {
            s[r]  += __shfl_xor(s[r],  m, 64);
            sq[r] += __shfl_xor(sq[r], m, 64);
        }
    float* Lred = (float*)(LDS + L_HS);   // 1KB scratch over Hs (all reads done)
    if (c == 0) {
        #pragma unroll
        for (int r = 0; r < 4; ++r) {
            int row = rowg * 16 + q * 4 + r;
            Lred[colsel * 128 + row]      = s[r];
            Lred[colsel * 128 + 64 + row] = sq[r];
        }
    }
    __syncthreads();
    float mu[4], rs[4];
    #pragma unroll
    for (int r = 0; r < 4; ++r) {
        int row = rowg * 16 + q * 4 + r;
        float ssum = Lred[row] + Lred[128 + row];
        float qsum = Lred[64 + row] + Lred[192 + row];
        float m_ = ssum * (1.0f / 256.0f);
        float var = qsum * (1.0f / 256.0f) - m_ * m_;
        mu[r] = m_;
        rs[r] = rsqrtf(var + 1e-5f);
    }
    #pragma unroll
    for (int cf = 0; cf < 8; ++cf) {
        int col = colsel * 128 + cf * 16 + c;
        float lw = lnw[col];
        float lb = lnb[col];
        #pragma unroll
        for (int r = 0; r < 4; ++r) {
            int grow = row0 + rowg * 16 + q * 4 + r;
            float v = (acc2[cf][r] - mu[r]) * rs[r] * lw + lb;
            float g = gelu_fast(v);
            size_t oi = ((size_t)grow * NBR + n) * DV + col;
            out[oi] = x[oi] + g;
        }
    }
#undef STAGE1
#undef STAGE2
}

extern "C" void kernel_launch(void* const* d_in, const int* in_sizes, int n_in,
                              void* d_out, int out_size, void* d_ws, size_t ws_size,
                              hipStream_t stream) {
    const float* x   = (const float*)d_in[0];
    const float* U1  = (const float*)d_in[1];
    const float* b1  = (const float*)d_in[2];
    const float* U2  = (const float*)d_in[3];
    const float* b2  = (const float*)d_in[4];
    const float* lnw = (const float*)d_in[5];
    const float* lnb = (const float*)d_in[6];
    float* out = (float*)d_out;

    unsigned short* w1img = (unsigned short*)d_ws;               // 4 MB (256 images x 16KB)
    unsigned short* w2img = w1img + (size_t)4 * 1024 * 1024 / 2; // 4 MB

    prep_weights<<<dim3(256), dim3(256), 0, stream>>>(U1, U2, w1img, w2img);
    belayer_main<<<dim3((NROWS / RT) * NBR), dim3(512), 0, stream>>>(x, w1img, w2img, b1, b2, lnw, lnb, out);
}